// Round 4
// baseline (102.968 us; speedup 1.0000x reference)
//
#include <hip/hip_runtime.h>

#define B   64
#define T   2000
#define DQ  1024
#define DM  512
#define D   128
#define F   32
#define KK  31
#define WIN 7
#define NCH 32
#define CH  63    // ceil(T/NCH)

// ws layout:
//   cnt  : [B] ints     @ float-offset 0   (zeroed via hipMemsetAsync each call)
//   part : [B][NCH][DM] @ float-offset 64
#define PART_OFF 64

// out layout (floats):
//   attention  [B][D]  @ 0
//   alignments [B][T]  @ 8192
//   next_state [B][T]  @ 8192 + B*T
//   max_att    [B]     @ 8192 + 2*B*T   (as float)
#define OUT_ALIGN 8192
#define OUT_NEXT  (8192 + B*T)
#define OUT_ARG   (8192 + 2*B*T)

// One kernel:
//  blocks [0,B)        : per-batch energies + softmax + all [B,T] outputs + argmax
//                        + (non-degenerate) window-ctx GEMV -> attention
//                        + (lowmem fallback) degenerate slow colsum + GEMV
//  blocks [B, B+B*NCH) : degenerate colsum partials; 32nd arriver per batch
//                        reduces partials (fixed order) + GEMV -> attention
__global__ void __launch_bounds__(512)
KF(const float* __restrict__ q, const float* __restrict__ mem,
   const float* __restrict__ pa, const int* __restrict__ pm, const int* __restrict__ ml,
   const float* __restrict__ Wq, const float* __restrict__ Wm,
   const float* __restrict__ ck, const float* __restrict__ cb,
   const float* __restrict__ Wloc, const float* __restrict__ sv,
   const float* __restrict__ sb, int* __restrict__ cnt, float* __restrict__ part,
   float* __restrict__ out, int lowmem) {
    // smem_a: qs[1024] during pq phase; later ctxs[512] + gpart[4][128]
    __shared__ float smem_a[DQ];
    __shared__ float pqpart[4][D];
    __shared__ float pqs[D];
    __shared__ float mrow[WIN][DM];
    __shared__ float fsh[WIN][F];
    __shared__ float2 pacc2[WIN][8][64];
    __shared__ float esh[WIN];
    __shared__ float ash[WIN];
    __shared__ int   sbest;
    __shared__ int   sflag;

    float* qs = smem_a;
    float* ctxs = smem_a;           // [DM], valid after pq phase
    float* gpart = smem_a + DM;     // [4][D]

    int blk = blockIdx.x;
    int tid = threadIdx.x;

    if (blk >= B) {
        // ---------------- degenerate colsum partial ----------------
        int idx = blk - B;
        int b = idx >> 5, c = idx & 31;
        if (pm[b] < ml[b]) return;              // non-degenerate batch: nothing
        int t0 = c * CH, t1 = t0 + CH;
        if (t1 > T) t1 = T;
        const float* mp = mem + ((size_t)b * T + t0) * DM + tid;
        float a0 = 0.f, a1 = 0.f, a2 = 0.f, a3 = 0.f;
        int t = t0;
        for (; t + 4 <= t1; t += 4) {
            a0 += mp[0];
            a1 += mp[DM];
            a2 += mp[2 * DM];
            a3 += mp[3 * DM];
            mp += 4 * (size_t)DM;
        }
        for (; t < t1; ++t) { a0 += *mp; mp += DM; }
        float acc = ((a0 + a1) + (a2 + a3)) * (1.f / (float)T);
        part[((size_t)b * NCH + c) * DM + tid] = acc;
        __threadfence();
        __syncthreads();
        if (tid == 0) sflag = (atomicAdd(&cnt[b], 1) == NCH - 1);
        __syncthreads();
        if (!sflag) return;
        // -------- last arriver: reduce partials (fixed order) + GEMV --------
        __threadfence();
        float s = 0.f;
        for (int cc = 0; cc < NCH; ++cc)
            s += part[((size_t)b * NCH + cc) * DM + tid];
        ctxs[tid] = s;
        __syncthreads();
        {
            int col = tid & 127, j = tid >> 7;
            const float* wp = Wm + (size_t)(j * 128) * D + col;
            float acc2 = 0.f;
            for (int mm = 0; mm < 128; ++mm)
                acc2 += ctxs[j * 128 + mm] * wp[(size_t)mm * D];
            gpart[j * D + col] = acc2;
        }
        __syncthreads();
        if (tid < D)
            out[b * D + tid] = gpart[tid] + gpart[D + tid] + gpart[2 * D + tid] + gpart[3 * D + tid];
        return;
    }

    // ---------------- per-batch energy / softmax / outputs ----------------
    int b = blk;
    int lane = tid & 63;
    int wave = tid >> 6;
    int p = pm[b], L = ml[b];
    int wstart = p, wlen = 0;
    if (p < L) { int we = p + WIN; if (we > L) we = L; wlen = we - p; }

    if (wlen > 0) {
        // stage q row
        qs[tid] = q[(size_t)b * DQ + tid];
        qs[tid + 512] = q[(size_t)b * DQ + tid + 512];
        // stage window memory rows (zero unused)
        for (int e = tid; e < WIN * DM; e += 512) {
            int i = e >> 9, m = e & 511;
            mrow[i][m] = (i < wlen) ? mem[((size_t)b * T + wstart + i) * DM + m] : 0.f;
        }
        // conv location features
        if (tid < WIN * F) {
            int i = tid >> 5, f = tid & 31;
            if (i < wlen) {
                int t = wstart + i;
                float acc = cb[f];
                for (int k = 0; k < KK; ++k) {
                    int tt = t + k - 15;
                    float x = (tt >= 0 && tt < T) ? pa[(size_t)b * T + tt] : 0.f;
                    acc += x * ck[k * F + f];
                }
                fsh[i][f] = acc;
            } else if (i < WIN) {
                fsh[i][f] = 0.f;
            }
        }
        __syncthreads();

        // pq partials: (j=tid>>7, d=tid&127), each sums 256 of 1024 k
        {
            int d = tid & 127, j = tid >> 7;
            int k0 = j * 256;
            float acc = 0.f;
            for (int k = 0; k < 256; ++k)
                acc += qs[k0 + k] * Wq[(size_t)(k0 + k) * D + d];
            pqpart[j][d] = acc;
        }
        __syncthreads();
        if (tid < D)
            pqs[tid] = pqpart[0][tid] + pqpart[1][tid] + pqpart[2][tid] + pqpart[3][tid] + sb[tid];

        // m-split energies: wave w owns rows [w*64, (w+1)*64), all WIN positions
        {
            const float2* Wm2 = (const float2*)Wm;
            float2 acc[WIN];
            #pragma unroll
            for (int i = 0; i < WIN; ++i) { acc[i].x = 0.f; acc[i].y = 0.f; }
            int m0 = wave * 64;
            for (int mm = 0; mm < 64; ++mm) {
                int m = m0 + mm;
                float2 wrow = Wm2[(size_t)m * 64 + lane];
                #pragma unroll
                for (int i = 0; i < WIN; ++i) {
                    float a = mrow[i][m];
                    acc[i].x += a * wrow.x;
                    acc[i].y += a * wrow.y;
                }
            }
            #pragma unroll
            for (int i = 0; i < WIN; ++i) pacc2[i][wave][lane] = acc[i];
        }
        __syncthreads();

        if (wave < wlen) {
            int i = wave;
            float2 s2 = {0.f, 0.f};
            #pragma unroll
            for (int w = 0; w < 8; ++w) {
                s2.x += pacc2[i][w][lane].x;
                s2.y += pacc2[i][w][lane].y;
            }
            const float2* Wl2 = (const float2*)Wloc;
            float p0 = 0.f, p1 = 0.f;
            #pragma unroll
            for (int f = 0; f < F; ++f) {
                float fv = fsh[i][f];
                float2 wv = Wl2[f * 64 + lane];
                p0 += fv * wv.x; p1 += fv * wv.y;
            }
            int c0 = 2 * lane, c1 = c0 + 1;
            float x = sv[c0] * tanhf(s2.x + pqs[c0] + p0)
                    + sv[c1] * tanhf(s2.y + pqs[c1] + p1);
            for (int o = 32; o > 0; o >>= 1) x += __shfl_xor(x, o);
            if (lane == 0) esh[i] = x;
        }
        __syncthreads();

        if (tid == 0) {
            float a[WIN];
            int best = 0;
            float mx = esh[0];
            for (int i = 1; i < wlen; ++i) if (esh[i] > mx) mx = esh[i];
            float s = 0.f;
            for (int i = 0; i < wlen; ++i) { a[i] = expf(esh[i] - mx); s += a[i]; }
            float inv = 1.f / s;
            float ab = -1.f;
            for (int i = 0; i < wlen; ++i) {
                a[i] *= inv;
                if (a[i] > ab) { ab = a[i]; best = i; }
            }
            for (int i = 0; i < WIN; ++i) ash[i] = (i < wlen) ? a[i] : 0.f;
            sbest = wstart + best;
        }
        __syncthreads();

        // window ctx -> attention GEMV (smem_a reused: qs dead after pq phase)
        {
            float s = 0.f;
            #pragma unroll
            for (int i = 0; i < WIN; ++i) s += ash[i] * mrow[i][tid];
            ctxs[tid] = s;
        }
        __syncthreads();
        {
            int col = tid & 127, j = tid >> 7;
            const float* wp = Wm + (size_t)(j * 128) * D + col;
            float acc2 = 0.f;
            for (int mm = 0; mm < 128; ++mm)
                acc2 += ctxs[j * 128 + mm] * wp[(size_t)mm * D];
            gpart[j * D + col] = acc2;
        }
        __syncthreads();
        if (tid < D)
            out[b * D + tid] = gpart[tid] + gpart[D + tid] + gpart[2 * D + tid] + gpart[3 * D + tid];
    } else if (lowmem) {
        // slow in-block degenerate colsum (only if ws too small for partials)
        const float* mp = mem + (size_t)b * T * DM + tid;
        float a0 = 0.f, a1 = 0.f, a2 = 0.f, a3 = 0.f;
        int t = 0;
        for (; t + 4 <= T; t += 4) {
            a0 += mp[0]; a1 += mp[DM]; a2 += mp[2 * DM]; a3 += mp[3 * DM];
            mp += 4 * (size_t)DM;
        }
        for (; t < T; ++t) { a0 += *mp; mp += DM; }
        ctxs[tid] = ((a0 + a1) + (a2 + a3)) * (1.f / (float)T);
        __syncthreads();
        {
            int col = tid & 127, j = tid >> 7;
            const float* wp = Wm + (size_t)(j * 128) * D + col;
            float acc2 = 0.f;
            for (int mm = 0; mm < 128; ++mm)
                acc2 += ctxs[j * 128 + mm] * wp[(size_t)mm * D];
            gpart[j * D + col] = acc2;
        }
        __syncthreads();
        if (tid < D)
            out[b * D + tid] = gpart[tid] + gpart[D + tid] + gpart[2 * D + tid] + gpart[3 * D + tid];
    }

    // ---------------- [B,T] outputs + argmax (all batches) ----------------
    {
        float invT = 1.f / (float)T;
        for (int t = tid; t < T; t += 512) {
            float a;
            if (wlen == 0) a = invT;
            else a = (t >= wstart && t < wstart + wlen) ? ash[t - wstart] : 0.f;
            out[OUT_ALIGN + b * T + t] = a;
            out[OUT_NEXT + b * T + t] = pa[(size_t)b * T + t] + a;
        }
        if (tid == 0) out[OUT_ARG + b] = (float)((wlen > 0) ? sbest : 0);
    }
}

extern "C" void kernel_launch(void* const* d_in, const int* in_sizes, int n_in,
                              void* d_out, int out_size, void* d_ws, size_t ws_size,
                              hipStream_t stream) {
    const float* query = (const float*)d_in[0];
    const float* memory = (const float*)d_in[1];
    const float* prev_align = (const float*)d_in[2];
    const int* prev_max = (const int*)d_in[3];
    const int* mem_len = (const int*)d_in[4];
    const float* Wq = (const float*)d_in[5];
    const float* Wm = (const float*)d_in[6];
    const float* ck = (const float*)d_in[7];
    const float* cb = (const float*)d_in[8];
    const float* Wloc = (const float*)d_in[9];
    const float* sv = (const float*)d_in[10];
    const float* sb = (const float*)d_in[11];
    float* out = (float*)d_out;

    int* cnt = (int*)d_ws;
    float* part = (float*)d_ws + PART_OFF;

    size_t need = (size_t)(PART_OFF + (size_t)B * NCH * DM) * 4;
    int lowmem = (ws_size < need) ? 1 : 0;

    if (!lowmem)
        hipMemsetAsync(cnt, 0, B * sizeof(int), stream);

    int grid = lowmem ? B : (B + B * NCH);
    KF<<<grid, 512, 0, stream>>>(query, memory, prev_align, prev_max, mem_len,
                                 Wq, Wm, ck, cb, Wloc, sv, sb,
                                 cnt, part, out, lowmem);
}

// Round 5
// 36.689 us; speedup vs baseline: 2.8065x; 2.8065x over previous
//
#include <hip/hip_runtime.h>

#define B   64
#define T   2000
#define DQ  1024
#define DM  512
#define D   128
#define F   32
#define KK  31
#define WIN 7
#define NCH 32
#define CH  63    // ceil(T/NCH)

// ws layout (floats):
//   part : [B][NCH][DM] @ 0   (1048576 floats)
// out layout (floats):
//   attention  [B][D]  @ 0
//   alignments [B][T]  @ 8192
//   next_state [B][T]  @ 8192 + B*T
//   max_att    [B]     @ 8192 + 2*B*T   (as float)
#define OUT_ALIGN 8192
#define OUT_NEXT  (8192 + B*T)
#define OUT_ARG   (8192 + 2*B*T)

// ---------------- K1 ----------------
//  blocks [0,B)        : per-batch energies + softmax + [B,T] outputs + argmax
//                        + (non-degenerate) window-ctx GEMV -> attention
//                        + (lowmem) in-block degenerate colsum + GEMV
//  blocks [B, B+B*NCH) : degenerate colsum partials -> part (no sync machinery)
__global__ void __launch_bounds__(512)
K1(const float* __restrict__ q, const float* __restrict__ mem,
   const float* __restrict__ pa, const int* __restrict__ pm, const int* __restrict__ ml,
   const float* __restrict__ Wq, const float* __restrict__ Wm,
   const float* __restrict__ ck, const float* __restrict__ cb,
   const float* __restrict__ Wloc, const float* __restrict__ sv,
   const float* __restrict__ sb, float* __restrict__ part,
   float* __restrict__ out, int lowmem) {
    __shared__ float smem_a[DQ];          // qs during pq; later ctxs[512]+gpart[512]
    __shared__ float pqpart[4][D];
    __shared__ float pqs[D];
    __shared__ float mrow[WIN][DM];
    __shared__ float fsh[WIN][F];
    __shared__ float2 pacc2[WIN][8][64];
    __shared__ float esh[WIN];
    __shared__ float ash[WIN];
    __shared__ int   sbest;

    float* qs = smem_a;
    float* ctxs = smem_a;
    float* gpart = smem_a + DM;

    int blk = blockIdx.x;
    int tid = threadIdx.x;

    if (blk >= B) {
        // ---------------- degenerate colsum partial ----------------
        int idx = blk - B;
        int b = idx >> 5, c = idx & 31;
        if (pm[b] < ml[b]) return;              // non-degenerate: nothing to do
        int t0 = c * CH, t1 = t0 + CH;
        if (t1 > T) t1 = T;
        const float* mp = mem + ((size_t)b * T + t0) * DM + tid;
        float a0 = 0.f, a1 = 0.f, a2 = 0.f, a3 = 0.f;
        int t = t0;
        for (; t + 4 <= t1; t += 4) {
            a0 += mp[0];
            a1 += mp[DM];
            a2 += mp[2 * DM];
            a3 += mp[3 * DM];
            mp += 4 * (size_t)DM;
        }
        for (; t < t1; ++t) { a0 += *mp; mp += DM; }
        part[((size_t)b * NCH + c) * DM + tid] = ((a0 + a1) + (a2 + a3)) * (1.f / (float)T);
        return;
    }

    // ---------------- per-batch energy / softmax / outputs ----------------
    int b = blk;
    int lane = tid & 63;
    int wave = tid >> 6;
    int p = pm[b], L = ml[b];
    int wstart = p, wlen = 0;
    if (p < L) { int we = p + WIN; if (we > L) we = L; wlen = we - p; }

    if (wlen > 0) {
        qs[tid] = q[(size_t)b * DQ + tid];
        qs[tid + 512] = q[(size_t)b * DQ + tid + 512];
        for (int e = tid; e < WIN * DM; e += 512) {
            int i = e >> 9, m = e & 511;
            mrow[i][m] = (i < wlen) ? mem[((size_t)b * T + wstart + i) * DM + m] : 0.f;
        }
        if (tid < WIN * F) {
            int i = tid >> 5, f = tid & 31;
            if (i < wlen) {
                int t = wstart + i;
                float acc = cb[f];
                for (int k = 0; k < KK; ++k) {
                    int tt = t + k - 15;
                    float x = (tt >= 0 && tt < T) ? pa[(size_t)b * T + tt] : 0.f;
                    acc += x * ck[k * F + f];
                }
                fsh[i][f] = acc;
            } else if (i < WIN) {
                fsh[i][f] = 0.f;
            }
        }
        __syncthreads();

        // pq partials: (j=tid>>7, d=tid&127), each sums 256 of 1024 k
        {
            int d = tid & 127, j = tid >> 7;
            int k0 = j * 256;
            float acc = 0.f;
            for (int k = 0; k < 256; ++k)
                acc += qs[k0 + k] * Wq[(size_t)(k0 + k) * D + d];
            pqpart[j][d] = acc;
        }
        __syncthreads();
        if (tid < D)
            pqs[tid] = pqpart[0][tid] + pqpart[1][tid] + pqpart[2][tid] + pqpart[3][tid] + sb[tid];

        // m-split energies: wave w owns rows [w*64,(w+1)*64), all WIN positions
        {
            const float2* Wm2 = (const float2*)Wm;
            float2 acc[WIN];
            #pragma unroll
            for (int i = 0; i < WIN; ++i) { acc[i].x = 0.f; acc[i].y = 0.f; }
            int m0 = wave * 64;
            for (int mm = 0; mm < 64; ++mm) {
                int m = m0 + mm;
                float2 wrow = Wm2[(size_t)m * 64 + lane];
                #pragma unroll
                for (int i = 0; i < WIN; ++i) {
                    float a = mrow[i][m];
                    acc[i].x += a * wrow.x;
                    acc[i].y += a * wrow.y;
                }
            }
            #pragma unroll
            for (int i = 0; i < WIN; ++i) pacc2[i][wave][lane] = acc[i];
        }
        __syncthreads();

        if (wave < wlen) {
            int i = wave;
            float2 s2 = {0.f, 0.f};
            #pragma unroll
            for (int w = 0; w < 8; ++w) {
                s2.x += pacc2[i][w][lane].x;
                s2.y += pacc2[i][w][lane].y;
            }
            const float2* Wl2 = (const float2*)Wloc;
            float p0 = 0.f, p1 = 0.f;
            #pragma unroll
            for (int f = 0; f < F; ++f) {
                float fv = fsh[i][f];
                float2 wv = Wl2[f * 64 + lane];
                p0 += fv * wv.x; p1 += fv * wv.y;
            }
            int c0 = 2 * lane, c1 = c0 + 1;
            float x = sv[c0] * tanhf(s2.x + pqs[c0] + p0)
                    + sv[c1] * tanhf(s2.y + pqs[c1] + p1);
            for (int o = 32; o > 0; o >>= 1) x += __shfl_xor(x, o);
            if (lane == 0) esh[i] = x;
        }
        __syncthreads();

        if (tid == 0) {
            float a[WIN];
            int best = 0;
            float mx = esh[0];
            for (int i = 1; i < wlen; ++i) if (esh[i] > mx) mx = esh[i];
            float s = 0.f;
            for (int i = 0; i < wlen; ++i) { a[i] = expf(esh[i] - mx); s += a[i]; }
            float inv = 1.f / s;
            float ab = -1.f;
            for (int i = 0; i < wlen; ++i) {
                a[i] *= inv;
                if (a[i] > ab) { ab = a[i]; best = i; }
            }
            for (int i = 0; i < WIN; ++i) ash[i] = (i < wlen) ? a[i] : 0.f;
            sbest = wstart + best;
        }
        __syncthreads();

        // window ctx -> attention GEMV (smem_a reused: qs dead after pq phase)
        {
            float s = 0.f;
            #pragma unroll
            for (int i = 0; i < WIN; ++i) s += ash[i] * mrow[i][tid];
            ctxs[tid] = s;
        }
        __syncthreads();
        {
            int col = tid & 127, j = tid >> 7;
            const float* wp = Wm + (size_t)(j * 128) * D + col;
            float acc2 = 0.f;
            for (int mm = 0; mm < 128; ++mm)
                acc2 += ctxs[j * 128 + mm] * wp[(size_t)mm * D];
            gpart[j * D + col] = acc2;
        }
        __syncthreads();
        if (tid < D)
            out[b * D + tid] = gpart[tid] + gpart[D + tid] + gpart[2 * D + tid] + gpart[3 * D + tid];
    } else if (lowmem) {
        // in-block degenerate colsum (only if ws too small for partials)
        const float* mp = mem + (size_t)b * T * DM + tid;
        float a0 = 0.f, a1 = 0.f, a2 = 0.f, a3 = 0.f;
        int t = 0;
        for (; t + 4 <= T; t += 4) {
            a0 += mp[0]; a1 += mp[DM]; a2 += mp[2 * DM]; a3 += mp[3 * DM];
            mp += 4 * (size_t)DM;
        }
        for (; t < T; ++t) { a0 += *mp; mp += DM; }
        ctxs[tid] = ((a0 + a1) + (a2 + a3)) * (1.f / (float)T);
        __syncthreads();
        {
            int col = tid & 127, j = tid >> 7;
            const float* wp = Wm + (size_t)(j * 128) * D + col;
            float acc2 = 0.f;
            for (int mm = 0; mm < 128; ++mm)
                acc2 += ctxs[j * 128 + mm] * wp[(size_t)mm * D];
            gpart[j * D + col] = acc2;
        }
        __syncthreads();
        if (tid < D)
            out[b * D + tid] = gpart[tid] + gpart[D + tid] + gpart[2 * D + tid] + gpart[3 * D + tid];
    }

    // ---------------- [B,T] outputs + argmax ----------------
    {
        float invT = 1.f / (float)T;
        for (int t = tid; t < T; t += 512) {
            float a;
            if (wlen == 0) a = invT;
            else a = (t >= wstart && t < wstart + wlen) ? ash[t - wstart] : 0.f;
            out[OUT_ALIGN + b * T + t] = a;
            out[OUT_NEXT + b * T + t] = pa[(size_t)b * T + t] + a;
        }
        if (tid == 0) out[OUT_ARG + b] = (float)((wlen > 0) ? sbest : 0);
    }
}

// ---------------- K2: degenerate reduce + attention GEMV only ----------------
__global__ void __launch_bounds__(512)
K2(const int* __restrict__ pm, const int* __restrict__ ml,
   const float* __restrict__ part, const float* __restrict__ Wm,
   float* __restrict__ out) {
    int b = blockIdx.x;
    if (pm[b] < ml[b]) return;                  // non-degenerate handled in K1
    int tid = threadIdx.x;                      // 512
    __shared__ float ctxs[DM];
    __shared__ float gpart[4 * D];
    float s = 0.f;
    #pragma unroll 8
    for (int cc = 0; cc < NCH; ++cc)
        s += part[((size_t)b * NCH + cc) * DM + tid];
    ctxs[tid] = s;
    __syncthreads();
    {
        int col = tid & 127, j = tid >> 7;
        const float* wp = Wm + (size_t)(j * 128) * D + col;
        float acc = 0.f;
        for (int mm = 0; mm < 128; ++mm)
            acc += ctxs[j * 128 + mm] * wp[(size_t)mm * D];
        gpart[j * D + col] = acc;
    }
    __syncthreads();
    if (tid < D)
        out[b * D + tid] = gpart[tid] + gpart[D + tid] + gpart[2 * D + tid] + gpart[3 * D + tid];
}

extern "C" void kernel_launch(void* const* d_in, const int* in_sizes, int n_in,
                              void* d_out, int out_size, void* d_ws, size_t ws_size,
                              hipStream_t stream) {
    const float* query = (const float*)d_in[0];
    const float* memory = (const float*)d_in[1];
    const float* prev_align = (const float*)d_in[2];
    const int* prev_max = (const int*)d_in[3];
    const int* mem_len = (const int*)d_in[4];
    const float* Wq = (const float*)d_in[5];
    const float* Wm = (const float*)d_in[6];
    const float* ck = (const float*)d_in[7];
    const float* cb = (const float*)d_in[8];
    const float* Wloc = (const float*)d_in[9];
    const float* sv = (const float*)d_in[10];
    const float* sb = (const float*)d_in[11];
    float* out = (float*)d_out;

    float* part = (float*)d_ws;
    size_t need = (size_t)B * NCH * DM * 4;
    int lowmem = (ws_size < need) ? 1 : 0;

    int grid = lowmem ? B : (B + B * NCH);
    K1<<<grid, 512, 0, stream>>>(query, memory, prev_align, prev_max, mem_len,
                                 Wq, Wm, ck, cb, Wloc, sv, sb, part, out, lowmem);
    if (!lowmem)
        K2<<<B, 512, 0, stream>>>(prev_max, mem_len, part, Wm, out);
}